// Round 28
// baseline (189.131 us; speedup 1.0000x reference)
//
#include <hip/hip_runtime.h>
#include <hip/hip_bf16.h>

// Problem constants
#define KN 2048
#define BB 4
#define DM 512
#define NH 8
#define HE 64
#define UP 40
#define NBH 32          // B*H
#define NROWS 8192      // KN*B
#define MiB(x) ((size_t)(x) << 20)

typedef __attribute__((ext_vector_type(8))) short short8;
typedef __attribute__((ext_vector_type(4))) float f32x4;

// bf16 split helpers (RNE)
__device__ __forceinline__ ushort f2bf(float x) {
  unsigned u = __float_as_uint(x);
  unsigned r = (u + 0x7FFFu + ((u >> 16) & 1u)) >> 16;
  return (ushort)r;
}
__device__ __forceinline__ float bf2f(ushort h) {
  return __uint_as_float((unsigned)h << 16);
}

// ---------------------------------------------------------------------------
// Fused split of the 3 weight matrices into hi/lo bf16 planes (stacked).
// ---------------------------------------------------------------------------
__global__ __launch_bounds__(256) void wsplit3_kernel(
    const float* __restrict__ W0, const float* __restrict__ W1,
    const float* __restrict__ W2, ushort* __restrict__ Wh,
    ushort* __restrict__ Wl) {
  const int which = blockIdx.x >> 9;
  const float* W = (which == 0) ? W0 : (which == 1) ? W1 : W2;
  size_t base = (size_t)which * 262144;
  int i = ((blockIdx.x & 511) * 256 + threadIdx.x) * 2;
  float2 v = *(const float2*)(W + i);
  ushort h0 = f2bf(v.x), h1 = f2bf(v.y);
  ushort l0 = f2bf(v.x - bf2f(h0)), l1 = f2bf(v.y - bf2f(h1));
  *(ushort2*)(Wh + base + i) = make_ushort2(h0, h1);
  *(ushort2*)(Wl + base + i) = make_ushort2(l0, l1);
}

// ---------------------------------------------------------------------------
// Fused 3-GEMM (R25 config + consumer-first k-loop ordering):
// A dbuf LDS w/ in-staging RNE split, W frags from global bf16 planes.
// BM=64 x BN=256, grid 768 = 3 x 256. Per k-step the MFMA dependencies
// (ds_read of buf[cur], W loads) are issued FIRST after the barrier; the
// next tile's STAGE_A (global loads + conversion VALU + ds_write) follows
// so its latency/VALU overlaps the MFMA cluster (G7 source-order hint).
// ---------------------------------------------------------------------------
#define APAD 40
__global__ __launch_bounds__(256) void gemm3_mfma(
    const float* __restrict__ A0, const float* __restrict__ A1,
    const float* __restrict__ A2,
    const ushort* __restrict__ Wh3, const ushort* __restrict__ Wl3,
    const float* __restrict__ bq, const float* __restrict__ bk,
    const float* __restrict__ bv, float* __restrict__ QKV) {
  __shared__ ushort AsH[2][64 * APAD];
  __shared__ ushort AsL[2][64 * APAD];

  const int which = blockIdx.x >> 8;
  const int local = blockIdx.x & 255;
  const int xcd = local & 7;
  const int idx = local >> 3;            // 0..31
  const int ot = idx >> 4;               // 0..1
  const int mt = xcd * 16 + (idx & 15);  // 0..127
  const int m0 = mt * 64, o0 = ot * 256;

  const float* A = (which == 0) ? A0 : (which == 1) ? A1 : A2;
  const ushort* Wh = Wh3 + (size_t)which * 262144;
  const ushort* Wl = Wl3 + (size_t)which * 262144;
  const float* bias = (which == 0) ? bq : (which == 1) ? bk : bv;
  float* C = QKV + (size_t)which * 8192 * 512;
  const float scale = (which == 0) ? 0.125f : 1.0f;

  const int tid = threadIdx.x;
  const int w = tid >> 6, lane = tid & 63;
  const int fr = lane & 15;            // fragment row
  const int kc = lane >> 4;            // k-chunk (8 bf16)

  f32x4 acc[4][4];
#pragma unroll
  for (int i = 0; i < 4; ++i)
#pragma unroll
    for (int j = 0; j < 4; ++j)
#pragma unroll
      for (int r = 0; r < 4; ++r) acc[i][j][r] = 0.f;

  const int srow0 = tid >> 3, sq0 = tid & 7;
  const int srow1 = (tid + 256) >> 3, sq1 = (tid + 256) & 7;

#define STAGE_A(BUF, K0)                                                    \
  do {                                                                      \
    float4 v0 = *(const float4*)(A + (size_t)(m0 + srow0) * 512 + (K0) + sq0 * 4); \
    float4 v1 = *(const float4*)(A + (size_t)(m0 + srow1) * 512 + (K0) + sq1 * 4); \
    ushort h0 = f2bf(v0.x), h1 = f2bf(v0.y), h2 = f2bf(v0.z), h3 = f2bf(v0.w); \
    *(ushort4*)(&AsH[BUF][srow0 * APAD + sq0 * 4]) = make_ushort4(h0, h1, h2, h3); \
    *(ushort4*)(&AsL[BUF][srow0 * APAD + sq0 * 4]) = make_ushort4(           \
        f2bf(v0.x - bf2f(h0)), f2bf(v0.y - bf2f(h1)),                        \
        f2bf(v0.z - bf2f(h2)), f2bf(v0.w - bf2f(h3)));                       \
    ushort g0 = f2bf(v1.x), g1 = f2bf(v1.y), g2 = f2bf(v1.z), g3 = f2bf(v1.w); \
    *(ushort4*)(&AsH[BUF][srow1 * APAD + sq1 * 4]) = make_ushort4(g0, g1, g2, g3); \
    *(ushort4*)(&AsL[BUF][srow1 * APAD + sq1 * 4]) = make_ushort4(           \
        f2bf(v1.x - bf2f(g0)), f2bf(v1.y - bf2f(g1)),                        \
        f2bf(v1.z - bf2f(g2)), f2bf(v1.w - bf2f(g3)));                       \
  } while (0)

  STAGE_A(0, 0);

#pragma unroll
  for (int it = 0; it < 16; ++it) {
    const int cur = it & 1;
    const int k0 = it * 32;
    __syncthreads();                   // buf[cur] staged

    // ---- consumer loads FIRST: MFMA deps start their latency now ----
    short8 ah[4], al[4], bh[4], bl[4];
#pragma unroll
    for (int i = 0; i < 4; ++i) {
      int off = (i * 16 + fr) * APAD + kc * 8;
      ah[i] = *(const short8*)(&AsH[cur][off]);
      al[i] = *(const short8*)(&AsL[cur][off]);
    }
#pragma unroll
    for (int j = 0; j < 4; ++j) {
      size_t off = (size_t)(o0 + w * 64 + j * 16 + fr) * 512 + k0 + kc * 8;
      bh[j] = *(const short8*)(Wh + off);
      bl[j] = *(const short8*)(Wl + off);
    }

    // ---- next tile staging overlaps the MFMA cluster below ----
    if (it + 1 < 16) STAGE_A(!cur ? 1 : 0, k0 + 32);

#pragma unroll
    for (int i = 0; i < 4; ++i)
#pragma unroll
      for (int j = 0; j < 4; ++j) {
        acc[i][j] = __builtin_amdgcn_mfma_f32_16x16x32_bf16(
            ah[i], bh[j], acc[i][j], 0, 0, 0);
        acc[i][j] = __builtin_amdgcn_mfma_f32_16x16x32_bf16(
            ah[i], bl[j], acc[i][j], 0, 0, 0);
        acc[i][j] = __builtin_amdgcn_mfma_f32_16x16x32_bf16(
            al[i], bh[j], acc[i][j], 0, 0, 0);
      }
  }

#pragma unroll
  for (int i = 0; i < 4; ++i)
#pragma unroll
    for (int j = 0; j < 4; ++j)
#pragma unroll
      for (int r = 0; r < 4; ++r) {
        int m = m0 + i * 16 + (lane >> 4) * 4 + r;
        int o = o0 + w * 64 + j * 16 + fr;
        C[(size_t)m * 512 + o] = (acc[i][j][r] + bias[o]) * scale;
      }
}

// ---------------------------------------------------------------------------
// prep3: horizontal fusion of transposeK(64x64 tiles, 1024) || mscore(16384)
// || meanv_part(256).  All depend only on Q/K/V. grid 17664.
// ---------------------------------------------------------------------------
__global__ __launch_bounds__(256) void prep3_kernel(
    const float* __restrict__ K, float* __restrict__ Kt,
    const float* __restrict__ Q, const int* __restrict__ idx,
    float* __restrict__ Mout, const float* __restrict__ V,
    float* __restrict__ vpart) {
  __shared__ float T[64][65];
  const int bid = blockIdx.x;
  const int tid = threadIdx.x;

  if (bid < 1024) {
    // ---- transposeK: 64x64 tile ----
    const int bh = bid & 31;
    const int nt = bid >> 5;            // 0..31
    const int b = bh >> 3, h = bh & 7;
    const int n0 = nt * 64;
#pragma unroll
    for (int i = 0; i < 4; ++i) {
      int flat = tid + i * 256;         // 0..1023
      int r = flat >> 4;                // 0..63
      int c4 = flat & 15;               // 0..15
      float4 v = *(const float4*)(K + (((size_t)(n0 + r) * 4 + b) * 8 + h) * 64 + c4 * 4);
      T[r][c4 * 4 + 0] = v.x; T[r][c4 * 4 + 1] = v.y;
      T[r][c4 * 4 + 2] = v.z; T[r][c4 * 4 + 3] = v.w;
    }
    __syncthreads();
    const int nl = tid & 63;
    const int eg = tid >> 6;            // 0..3
#pragma unroll
    for (int e = eg * 16; e < eg * 16 + 16; ++e)
      Kt[((size_t)bh * 64 + e) * 2048 + n0 + nl] = T[nl][e];
    return;
  }

  if (bid < 1024 + 16384) {
    // ---- mscore (R10 verified body) ----
    const int vb = bid - 1024;
    const int bh = vb & 31;
    const int c  = vb >> 5;              // 0..511
    const int wv = tid >> 6;
    const int lane = tid & 63;
    const int n = c * 4 + wv;
    const int b = bh >> 3, h = bh & 7;
    const int g = lane >> 4;
    const int e16 = lane & 15;

    const float4 qv = *(const float4*)(Q + (((size_t)n * 4 + b) * 8 + h) * 64 + e16 * 4);

    float mx = -INFINITY, sm = 0.f;
#pragma unroll
    for (int it = 0; it < 10; ++it) {
      const int s = it * 4 + g;
      const int kn = idx[n * UP + s];
      const float4 kv = *(const float4*)(K + (((size_t)kn * 4 + b) * 8 + h) * 64 + e16 * 4);
      float d = qv.x * kv.x + qv.y * kv.y + qv.z * kv.z + qv.w * kv.w;
      d += __shfl_xor(d, 1);
      d += __shfl_xor(d, 2);
      d += __shfl_xor(d, 4);
      d += __shfl_xor(d, 8);
      mx = fmaxf(mx, d);
      sm += d;
    }
    mx = fmaxf(mx, __shfl_xor(mx, 16));
    mx = fmaxf(mx, __shfl_xor(mx, 32));
    sm += __shfl_xor(sm, 16);
    sm += __shfl_xor(sm, 32);
    if (lane == 0) Mout[(size_t)bh * 2048 + n] = mx - sm * (1.0f / (float)KN);
    return;
  }

  // ---- meanv_part ----
  {
    const int vb = bid - 17408;          // 0..255
    const int rc = vb >> 3;
    const int cc = vb & 7;
    const int c = cc * 256 + tid;
    const float* p = V + (size_t)rc * 64 * 2048 + c;
    float acc = 0.f;
#pragma unroll 8
    for (int i = 0; i < 64; ++i) acc += p[(size_t)i * 2048];
    vpart[(size_t)rc * 2048 + c] = acc;
  }
}

// ---------------------------------------------------------------------------
// sel2: topk(32) || meanv_final(8). grid 40.
// ---------------------------------------------------------------------------
__global__ __launch_bounds__(256) void sel2_kernel(
    const float* __restrict__ M, int* __restrict__ Mtop,
    const float* __restrict__ part, float* __restrict__ mnV) {
  __shared__ unsigned keys[2048];
  __shared__ int hist[256];
  __shared__ int suf[256];
  __shared__ int scal[2];
  __shared__ int ties[128];
  __shared__ int cnts[2];
  const int tid = threadIdx.x;

  if (blockIdx.x >= 32) {
    const int c = (blockIdx.x - 32) * 256 + tid;
    float acc = 0.f;
#pragma unroll
    for (int r = 0; r < 32; ++r) acc += part[(size_t)r * 2048 + c];
    mnV[c] = acc * (1.0f / (float)KN);
    return;
  }

  const int bh = blockIdx.x;
  const float* Mrow = M + (size_t)bh * 2048;
#pragma unroll
  for (int i = 0; i < 8; ++i) {
    int j = tid + i * 256;
    unsigned u = __float_as_uint(Mrow[j]);
    keys[j] = (u & 0x80000000u) ? ~u : (u | 0x80000000u);
  }
  if (tid < 2) cnts[tid] = 0;

  unsigned prefix = 0, prefmask = 0;
  int rank = UP;
#pragma unroll
  for (int shift = 24; shift >= 0; shift -= 8) {
    hist[tid] = 0;
    __syncthreads();
#pragma unroll
    for (int i = 0; i < 8; ++i) {
      unsigned k = keys[tid + i * 256];
      if ((k & prefmask) == prefix)
        atomicAdd(&hist[(k >> shift) & 0xFFu], 1);
    }
    __syncthreads();
    suf[tid] = hist[tid];
    __syncthreads();
#pragma unroll
    for (int off = 1; off < 256; off <<= 1) {
      int add = (tid + off < 256) ? suf[tid + off] : 0;
      __syncthreads();
      suf[tid] += add;
      __syncthreads();
    }
    {
      int above = suf[tid] - hist[tid];
      if (above < rank && rank <= suf[tid]) {
        scal[0] = tid;
        scal[1] = rank - above;
      }
    }
    __syncthreads();
    prefix |= ((unsigned)scal[0]) << shift;
    prefmask |= 0xFFu << shift;
    rank = scal[1];
    __syncthreads();
  }
  const unsigned T = prefix;

#pragma unroll
  for (int i = 0; i < 8; ++i) {
    int j = tid + i * 256;
    unsigned k = keys[j];
    if (k > T) {
      int p = atomicAdd(&cnts[0], 1);
      Mtop[bh * UP + p] = j;
    } else if (k == T) {
      int p = atomicAdd(&cnts[1], 1);
      if (p < 128) ties[p] = j;
    }
  }
  __syncthreads();
  if (tid == 0) {
    int base = cnts[0];
    int need = UP - base;
    int tc = cnts[1] < 128 ? cnts[1] : 128;
    for (int s = 0; s < need; ++s) {
      int best = 1 << 30, bj = 0;
      for (int j = 0; j < tc; ++j) {
        int v = ties[j];
        if (v < best) { best = v; bj = j; }
      }
      Mtop[bh * UP + base + s] = best;
      ties[bj] = 1 << 30;
    }
  }
}

// ---------------------------------------------------------------------------
// attnmean: attn_part(1024, R15 verified) || meanout(32). grid 1056.
// ---------------------------------------------------------------------------
#define QG 5   // queries per block
#define NC 4   // n-chunks
__global__ __launch_bounds__(256) void attnmean_kernel(
    const float* __restrict__ Q, const float* __restrict__ Kt,
    const float* __restrict__ V, const int* __restrict__ Mtop,
    float* __restrict__ pmax, float* __restrict__ psum,
    float* __restrict__ pvp, const float* __restrict__ mnV,
    const float* __restrict__ Wo, const float* __restrict__ bo,
    float* __restrict__ mo) {
  __shared__ float qs[QG][64];
  __shared__ float p[QG][512];
  __shared__ float redm[QG][4];
  __shared__ float reds[QG][4];
  __shared__ float pvs[4][QG][64];
  const int tid = threadIdx.x;

  if (blockIdx.x >= 1024) {
    // ---- meanout ----
    const int mb = blockIdx.x - 1024;       // 0..31
    const int b = mb >> 3;
    const int oc = mb & 7;
    const int ol = tid & 63;
    const int kp = tid >> 6;
    const int o = oc * 64 + ol;
    const float* m = mnV + b * 512;
    const float* w = Wo + (size_t)o * 512;
    float acc = 0.f;
#pragma unroll 8
    for (int k = kp * 128; k < kp * 128 + 128; ++k)
      acc = fmaf(m[k], w[k], acc);
    __shared__ float red[4][64];
    red[kp][ol] = acc;
    __syncthreads();
    if (tid < 64) {
      float s = red[0][ol] + red[1][ol] + red[2][ol] + red[3][ol];
      mo[b * 512 + o] = s + bo[o];
    }
    return;
  }

  const int bh = blockIdx.x & 31;
  const int t  = blockIdx.x >> 5;
  const int g  = t & 7;
  const int ch = t >> 3;
  const int b = bh >> 3, h = bh & 7;
  const int wv = tid >> 6, lane = tid & 63;
  const int n0 = ch * 512;

  for (int i = tid; i < QG * 64; i += 256) {
    int q = i >> 6, e = i & 63;
    int nq = Mtop[bh * UP + g * QG + q];
    qs[q][e] = Q[(((size_t)nq * 4 + b) * 8 + h) * 64 + e];
  }
  __syncthreads();

  const float* ktb = Kt + (size_t)bh * 64 * 2048;
  float d0[QG] = {}, d1[QG] = {};
  const int nb = n0 + tid * 2;
  for (int e = 0; e < 64; ++e) {
    float2 kv = *(const float2*)(ktb + (size_t)e * 2048 + nb);
#pragma unroll
    for (int q = 0; q < QG; ++q) {
      float qe = qs[q][e];
      d0[q] = fmaf(qe, kv.x, d0[q]);
      d1[q] = fmaf(qe, kv.y, d1[q]);
    }
  }

#pragma unroll
  for (int q = 0; q < QG; ++q) {
    float m_ = fmaxf(d0[q], d1[q]);
#pragma unroll
    for (int off = 1; off < 64; off <<= 1)
      m_ = fmaxf(m_, __shfl_xor(m_, off));
    if (lane == 0) redm[q][wv] = m_;
  }
  __syncthreads();
  float gm[QG];
#pragma unroll
  for (int q = 0; q < QG; ++q)
    gm[q] = fmaxf(fmaxf(redm[q][0], redm[q][1]),
                  fmaxf(redm[q][2], redm[q][3]));

  float ls[QG];
#pragma unroll
  for (int q = 0; q < QG; ++q) {
    float e0 = __expf(d0[q] - gm[q]);
    float e1 = __expf(d1[q] - gm[q]);
    p[q][tid * 2] = e0;
    p[q][tid * 2 + 1] = e1;
    ls[q] = e0 + e1;
  }
#pragma unroll
  for (int q = 0; q < QG; ++q) {
    float s_ = ls[q];
#pragma unroll
    for (int off = 1; off < 64; off <<= 1)
      s_ += __shfl_xor(s_, off);
    if (lane == 0) reds[q][wv] = s_;
  }
  __syncthreads();
  float den[QG];
#pragma unroll
  for (int q = 0; q < QG; ++q)
    den[q] = reds[q][0] + reds[q][1] + reds[q][2] + reds[q][3];

  float acc[QG] = {};
  for (int nn = wv * 128; nn < wv * 128 + 128; ++nn) {
    float v = V[(((size_t)(n0 + nn) * 4 + b) * 8 + h) * 64 + lane];
#pragma unroll
    for (int q = 0; q < QG; ++q) acc[q] = fmaf(p[q][nn], v, acc[q]);
  }
#pragma unroll
  for (int q = 0; q < QG; ++q) pvs[wv][q][lane] = acc[q];
  __syncthreads();

  for (int i = tid; i < QG * 64; i += 256) {
    int q = i >> 6, e = i & 63;
    int slot = bh * UP + g * QG + q;
    float pv = pvs[0][q][e] + pvs[1][q][e] + pvs[2][q][e] + pvs[3][q][e];
    pvp[((size_t)slot * NC + ch) * 64 + e] = pv;
    if (e == 0) {
      pmax[slot * NC + ch] = gm[q];
      psum[slot * NC + ch] = den[q];
    }
  }
}

// ---------------------------------------------------------------------------
// fill2: fillsel(1280) || fillout(4096). grid 5376. Disjoint outputs.
// ---------------------------------------------------------------------------
__global__ __launch_bounds__(256) void fill2_kernel(
    const int* __restrict__ Mtop, const float* __restrict__ mnV,
    float* __restrict__ ctx, const float* __restrict__ mo,
    float* __restrict__ out) {
  const int tid = threadIdx.x;
  if (blockIdx.x < 1280) {
    if (tid < 128) {
      const int i = blockIdx.x;
      const int b = (i / UP) >> 3;
      const int row = b * 2048 + Mtop[i];
      float4 v = *(const float4*)(mnV + b * 512 + tid * 4);
      *(float4*)(ctx + (size_t)row * 512 + tid * 4) = v;
    }
    return;
  }
  size_t i = ((size_t)(blockIdx.x - 1280) * 256 + tid) * 4;
  int d = (int)(i & 511);
  int b = (int)(i >> 20);
  float4 v = *(const float4*)(mo + (b << 9) + d);
  *(float4*)(out + i) = v;
}

// ---------------------------------------------------------------------------
// combine_scatter: flash-combine the NC chunk partials and write the result
// DIRECTLY into ctx (h-slices disjoint per slot -> deterministic).
// ---------------------------------------------------------------------------
__global__ __launch_bounds__(64) void combine_scatter_kernel(
    const float* __restrict__ pmax, const float* __restrict__ psum,
    const float* __restrict__ pvp, const int* __restrict__ Mtop,
    float* __restrict__ ctx) {
  const int slot = blockIdx.x;     // bh*40 + s
  const int e = threadIdx.x;
  const int bh = slot / UP;
  const int b = bh >> 3, h = bh & 7;
  const int n = Mtop[slot];
  float m = -INFINITY;
#pragma unroll
  for (int ch = 0; ch < NC; ++ch) m = fmaxf(m, pmax[slot * NC + ch]);
  float den = 0.f, num = 0.f;
#pragma unroll
  for (int ch = 0; ch < NC; ++ch) {
    float w = __expf(pmax[slot * NC + ch] - m);
    den = fmaf(w, psum[slot * NC + ch], den);
    num = fmaf(w, pvp[((size_t)slot * NC + ch) * 64 + e], num);
  }
  ctx[((size_t)(b * 2048 + n)) * 512 + h * 64 + e] = num / den;
}

// ---------------------------------------------------------------------------
// Sparse output GEMM over the 1280 Mtop rows (R23, verified).
// ---------------------------------------------------------------------------
__global__ __launch_bounds__(256) void gemm_rows(
    const float* __restrict__ ctx, const float* __restrict__ W,
    const float* __restrict__ bias, const int* __restrict__ Mtop,
    float* __restrict__ out) {
  __shared__ float As[32][36];
  __shared__ float Ws[32][68];
  __shared__ int rsel[32];
  const int rt = blockIdx.x >> 3;
  const int ot = blockIdx.x & 7;
  const int o0 = ot * 64;
  const int tid = threadIdx.x;
  const int tx = tid & 15;
  const int ty = tid >> 4;

  if (tid < 32) {
    int g = rt * 32 + tid;
    int b = (g / UP) >> 3;
    rsel[tid] = b * 2048 + Mtop[g];
  }
  __syncthreads();

  float acc[2][4] = {};
  for (int k0 = 0; k0 < 512; k0 += 32) {
    {
      int row = tid >> 3, q = tid & 7;
      float4 av = *(const float4*)(ctx + (size_t)rsel[row] * 512 + k0 + q * 4);
      As[q * 4 + 0][row] = av.x; As[q * 4 + 1][row] = av.y;
      As[q * 4 + 2][row] = av.z; As[q * 4 + 3][row] = av.w;
    }
#pragma unroll
    for (int i = 0; i < 2; ++i) {
      int flat = tid + i * 256;
      int r = flat >> 3, q = flat & 7;
      float4 wv = *(const float4*)(W + (size_t)(o0 + r) * 512 + k0 + q * 4);
      Ws[q * 4 + 0][r] = wv.x; Ws[q * 4 + 1][r] = wv.y;
      Ws[q * 4 + 2][r] = wv.z; Ws[q * 4 + 3][r] = wv.w;
    }
    __syncthreads();
#pragma unroll
    for (int kk = 0; kk < 32; ++kk) {
      float a_[2], w_[4];
#pragma unroll
      for (int i = 0; i < 2; ++i) a_[i] = As[kk][ty * 2 + i];
#pragma unroll
      for (int j = 0; j < 4; ++j) w_[j] = Ws[kk][tx * 4 + j];
#pragma unroll
      for (int i = 0; i < 2; ++i)
#pragma unroll
        for (int j = 0; j < 4; ++j)
          acc[i][j] = fmaf(a_[i], w_[j], acc[i][j]);
    }
    __syncthreads();
  }

#pragma unroll
  for (int i = 0; i < 2; ++i) {
    int m = rsel[ty * 2 + i];
#pragma unroll
    for (int j = 0; j < 4; ++j) {
      int o = o0 + tx * 4 + j;
      out[(size_t)m * 512 + o] = acc[i][j] + bias[o];
    }
  }
}

// ---------------------------------------------------------------------------
// Workspace layout (~70 MiB used; ws >= 113 MiB proven in R4):
//   [0, 256K) Mbuf | [589824,598016) mnV | [598016,603136) Mtop
//   [634880,897024) vpart | [941312,949504) mo
//   [1M,49M) QKV stacked (Q 1-17M = ctx alias, K 17-33M, V 33-49M)
//   [49M,65M) Kt | [65M,66.5M) Wh3 | [66.5M,68M) Wl3
//   [68M..68M+64K) pmax/psum | [..~69.4M) pvp
// ---------------------------------------------------------------------------
extern "C" void kernel_launch(void* const* d_in, const int* in_sizes, int n_in,
                              void* d_out, int out_size, void* d_ws,
                              size_t ws_size, hipStream_t stream) {
  const float* query = (const float*)d_in[0];
  const float* key   = (const float*)d_in[1];
  const float* value = (const float*)d_in[2];
  const int*   idxs  = (const int*)d_in[3];
  const float* Wq = (const float*)d_in[4];
  const float* bq = (const float*)d_in[5];
  const float* Wk = (const float*)d_in[6];
  const float* bk = (const float*)d_in[7];
  const float* Wv = (const float*)d_in[8];
  const float* bv = (const float*)d_in[9];
  const float* Wo = (const float*)d_in[10];
  const float* bo = (const float*)d_in[11];
  float* out = (float*)d_out;    // reference output dtype is float32

  char* ws = (char*)d_ws;
  float*  Mbuf  = (float*)(ws + 0);
  float*  mnV   = (float*)(ws + 589824);
  int*    Mtop  = (int*)  (ws + 598016);
  float*  vpart = (float*)(ws + 634880);
  float*  mo    = (float*)(ws + 941312);
  float*  QKV   = (float*)(ws + MiB(1));   // Q | K | V stacked
  float*  Q     = QKV;
  float*  K     = (float*)(ws + MiB(17));
  float*  V     = (float*)(ws + MiB(33));
  float*  Kt    = (float*)(ws + MiB(49));
  ushort* Wh3   = (ushort*)(ws + MiB(65));
  ushort* Wl3   = (ushort*)(ws + MiB(65) + 1572864);
  float*  pmax  = (float*)(ws + MiB(68));
  float*  psum  = (float*)(ws + MiB(68) + 32768);
  float*  pvp   = (float*)(ws + MiB(68) + 65536);
  float*  ctx   = Q;   // Q dead after attn; ctx written afterwards

  wsplit3_kernel<<<1536, 256, 0, stream>>>(Wq, Wk, Wv, Wh3, Wl3);
  gemm3_mfma<<<768, 256, 0, stream>>>(query, key, value, Wh3, Wl3,
                                      bq, bk, bv, QKV);

  prep3_kernel<<<17664, 256, 0, stream>>>(K, Kt, Q, idxs, Mbuf, V, vpart);
  sel2_kernel<<<40, 256, 0, stream>>>(Mbuf, Mtop, vpart, mnV);

  attnmean_kernel<<<1056, 256, 0, stream>>>(Q, Kt, V, Mtop, pmax, psum, pvp,
                                            mnV, Wo, bo, mo);
  fill2_kernel<<<5376, 256, 0, stream>>>(Mtop, mnV, ctx, mo, out);
  combine_scatter_kernel<<<NBH * UP, 64, 0, stream>>>(pmax, psum, pvp,
                                                      Mtop, ctx);
  gemm_rows<<<320, 256, 0, stream>>>(ctx, Wo, bo, Mtop, out);
}

// Round 29
// 170.152 us; speedup vs baseline: 1.1115x; 1.1115x over previous
//
#include <hip/hip_runtime.h>
#include <hip/hip_bf16.h>

// Problem constants
#define KN 2048
#define BB 4
#define DM 512
#define NH 8
#define HE 64
#define UP 40
#define NBH 32          // B*H
#define NROWS 8192      // KN*B
#define MiB(x) ((size_t)(x) << 20)

typedef __attribute__((ext_vector_type(8))) short short8;
typedef __attribute__((ext_vector_type(4))) float f32x4;

// bf16 split helpers (RNE)
__device__ __forceinline__ ushort f2bf(float x) {
  unsigned u = __float_as_uint(x);
  unsigned r = (u + 0x7FFFu + ((u >> 16) & 1u)) >> 16;
  return (ushort)r;
}
__device__ __forceinline__ float bf2f(ushort h) {
  return __uint_as_float((unsigned)h << 16);
}

// ---------------------------------------------------------------------------
// Fused split of the 3 weight matrices into hi/lo bf16 planes (stacked).
// ---------------------------------------------------------------------------
__global__ __launch_bounds__(256) void wsplit3_kernel(
    const float* __restrict__ W0, const float* __restrict__ W1,
    const float* __restrict__ W2, ushort* __restrict__ Wh,
    ushort* __restrict__ Wl) {
  const int which = blockIdx.x >> 9;
  const float* W = (which == 0) ? W0 : (which == 1) ? W1 : W2;
  size_t base = (size_t)which * 262144;
  int i = ((blockIdx.x & 511) * 256 + threadIdx.x) * 2;
  float2 v = *(const float2*)(W + i);
  ushort h0 = f2bf(v.x), h1 = f2bf(v.y);
  ushort l0 = f2bf(v.x - bf2f(h0)), l1 = f2bf(v.y - bf2f(h1));
  *(ushort2*)(Wh + base + i) = make_ushort2(h0, h1);
  *(ushort2*)(Wl + base + i) = make_ushort2(l0, l1);
}

// ---------------------------------------------------------------------------
// Fused 3-GEMM (R25/R27 best-measured config): A dbuf LDS w/ in-staging RNE
// split, W frags from global bf16 planes (L2-resident). BM=64 x BN=256,
// grid 768 = 3 x 256; which = bid>>8. ONE barrier per k-step (stage buf^1
// before compute on buf). 3-term split (AhWh+AhWl+AlWh).
// xcd = local&7 -> per-XCD A slice 2MB (L2-fits).
// NOTE (R28 post-mortem): consumer-first reordering regressed 71->98us
// (VGPR pressure from fragments live across STAGE_A). Keep THIS order.
// ---------------------------------------------------------------------------
#define APAD 40
__global__ __launch_bounds__(256) void gemm3_mfma(
    const float* __restrict__ A0, const float* __restrict__ A1,
    const float* __restrict__ A2,
    const ushort* __restrict__ Wh3, const ushort* __restrict__ Wl3,
    const float* __restrict__ bq, const float* __restrict__ bk,
    const float* __restrict__ bv, float* __restrict__ QKV) {
  __shared__ ushort AsH[2][64 * APAD];
  __shared__ ushort AsL[2][64 * APAD];

  const int which = blockIdx.x >> 8;
  const int local = blockIdx.x & 255;
  const int xcd = local & 7;
  const int idx = local >> 3;            // 0..31
  const int ot = idx >> 4;               // 0..1
  const int mt = xcd * 16 + (idx & 15);  // 0..127
  const int m0 = mt * 64, o0 = ot * 256;

  const float* A = (which == 0) ? A0 : (which == 1) ? A1 : A2;
  const ushort* Wh = Wh3 + (size_t)which * 262144;
  const ushort* Wl = Wl3 + (size_t)which * 262144;
  const float* bias = (which == 0) ? bq : (which == 1) ? bk : bv;
  float* C = QKV + (size_t)which * 8192 * 512;
  const float scale = (which == 0) ? 0.125f : 1.0f;

  const int tid = threadIdx.x;
  const int w = tid >> 6, lane = tid & 63;
  const int fr = lane & 15;            // fragment row
  const int kc = lane >> 4;            // k-chunk (8 bf16)

  f32x4 acc[4][4];
#pragma unroll
  for (int i = 0; i < 4; ++i)
#pragma unroll
    for (int j = 0; j < 4; ++j)
#pragma unroll
      for (int r = 0; r < 4; ++r) acc[i][j][r] = 0.f;

  const int srow0 = tid >> 3, sq0 = tid & 7;
  const int srow1 = (tid + 256) >> 3, sq1 = (tid + 256) & 7;

#define STAGE_A(BUF, K0)                                                    \
  do {                                                                      \
    float4 v0 = *(const float4*)(A + (size_t)(m0 + srow0) * 512 + (K0) + sq0 * 4); \
    float4 v1 = *(const float4*)(A + (size_t)(m0 + srow1) * 512 + (K0) + sq1 * 4); \
    ushort h0 = f2bf(v0.x), h1 = f2bf(v0.y), h2 = f2bf(v0.z), h3 = f2bf(v0.w); \
    *(ushort4*)(&AsH[BUF][srow0 * APAD + sq0 * 4]) = make_ushort4(h0, h1, h2, h3); \
    *(ushort4*)(&AsL[BUF][srow0 * APAD + sq0 * 4]) = make_ushort4(           \
        f2bf(v0.x - bf2f(h0)), f2bf(v0.y - bf2f(h1)),                        \
        f2bf(v0.z - bf2f(h2)), f2bf(v0.w - bf2f(h3)));                       \
    ushort g0 = f2bf(v1.x), g1 = f2bf(v1.y), g2 = f2bf(v1.z), g3 = f2bf(v1.w); \
    *(ushort4*)(&AsH[BUF][srow1 * APAD + sq1 * 4]) = make_ushort4(g0, g1, g2, g3); \
    *(ushort4*)(&AsL[BUF][srow1 * APAD + sq1 * 4]) = make_ushort4(           \
        f2bf(v1.x - bf2f(g0)), f2bf(v1.y - bf2f(g1)),                        \
        f2bf(v1.z - bf2f(g2)), f2bf(v1.w - bf2f(g3)));                       \
  } while (0)

  STAGE_A(0, 0);

#pragma unroll
  for (int it = 0; it < 16; ++it) {
    const int cur = it & 1;
    const int k0 = it * 32;
    __syncthreads();
    if (it + 1 < 16) STAGE_A(!cur ? 1 : 0, k0 + 32);

    short8 ah[4], al[4], bh[4], bl[4];
#pragma unroll
    for (int i = 0; i < 4; ++i) {
      int off = (i * 16 + fr) * APAD + kc * 8;
      ah[i] = *(const short8*)(&AsH[cur][off]);
      al[i] = *(const short8*)(&AsL[cur][off]);
    }
#pragma unroll
    for (int j = 0; j < 4; ++j) {
      size_t off = (size_t)(o0 + w * 64 + j * 16 + fr) * 512 + k0 + kc * 8;
      bh[j] = *(const short8*)(Wh + off);
      bl[j] = *(const short8*)(Wl + off);
    }
#pragma unroll
    for (int i = 0; i < 4; ++i)
#pragma unroll
      for (int j = 0; j < 4; ++j) {
        acc[i][j] = __builtin_amdgcn_mfma_f32_16x16x32_bf16(
            ah[i], bh[j], acc[i][j], 0, 0, 0);
        acc[i][j] = __builtin_amdgcn_mfma_f32_16x16x32_bf16(
            ah[i], bl[j], acc[i][j], 0, 0, 0);
        acc[i][j] = __builtin_amdgcn_mfma_f32_16x16x32_bf16(
            al[i], bh[j], acc[i][j], 0, 0, 0);
      }
  }

#pragma unroll
  for (int i = 0; i < 4; ++i)
#pragma unroll
    for (int j = 0; j < 4; ++j)
#pragma unroll
      for (int r = 0; r < 4; ++r) {
        int m = m0 + i * 16 + (lane >> 4) * 4 + r;
        int o = o0 + w * 64 + j * 16 + fr;
        C[(size_t)m * 512 + o] = (acc[i][j][r] + bias[o]) * scale;
      }
}

// ---------------------------------------------------------------------------
// prep3: horizontal fusion of transposeK(64x64 tiles, 1024) || mscore(16384)
// || meanv_part(256).  All depend only on Q/K/V. grid 17664.
// ---------------------------------------------------------------------------
__global__ __launch_bounds__(256) void prep3_kernel(
    const float* __restrict__ K, float* __restrict__ Kt,
    const float* __restrict__ Q, const int* __restrict__ idx,
    float* __restrict__ Mout, const float* __restrict__ V,
    float* __restrict__ vpart) {
  __shared__ float T[64][65];
  const int bid = blockIdx.x;
  const int tid = threadIdx.x;

  if (bid < 1024) {
    // ---- transposeK: 64x64 tile ----
    const int bh = bid & 31;
    const int nt = bid >> 5;            // 0..31
    const int b = bh >> 3, h = bh & 7;
    const int n0 = nt * 64;
#pragma unroll
    for (int i = 0; i < 4; ++i) {
      int flat = tid + i * 256;         // 0..1023
      int r = flat >> 4;                // 0..63
      int c4 = flat & 15;               // 0..15
      float4 v = *(const float4*)(K + (((size_t)(n0 + r) * 4 + b) * 8 + h) * 64 + c4 * 4);
      T[r][c4 * 4 + 0] = v.x; T[r][c4 * 4 + 1] = v.y;
      T[r][c4 * 4 + 2] = v.z; T[r][c4 * 4 + 3] = v.w;
    }
    __syncthreads();
    const int nl = tid & 63;
    const int eg = tid >> 6;            // 0..3
#pragma unroll
    for (int e = eg * 16; e < eg * 16 + 16; ++e)
      Kt[((size_t)bh * 64 + e) * 2048 + n0 + nl] = T[nl][e];
    return;
  }

  if (bid < 1024 + 16384) {
    // ---- mscore (R10 verified body) ----
    const int vb = bid - 1024;
    const int bh = vb & 31;
    const int c  = vb >> 5;              // 0..511
    const int wv = tid >> 6;
    const int lane = tid & 63;
    const int n = c * 4 + wv;
    const int b = bh >> 3, h = bh & 7;
    const int g = lane >> 4;
    const int e16 = lane & 15;

    const float4 qv = *(const float4*)(Q + (((size_t)n * 4 + b) * 8 + h) * 64 + e16 * 4);

    float mx = -INFINITY, sm = 0.f;
#pragma unroll
    for (int it = 0; it < 10; ++it) {
      const int s = it * 4 + g;
      const int kn = idx[n * UP + s];
      const float4 kv = *(const float4*)(K + (((size_t)kn * 4 + b) * 8 + h) * 64 + e16 * 4);
      float d = qv.x * kv.x + qv.y * kv.y + qv.z * kv.z + qv.w * kv.w;
      d += __shfl_xor(d, 1);
      d += __shfl_xor(d, 2);
      d += __shfl_xor(d, 4);
      d += __shfl_xor(d, 8);
      mx = fmaxf(mx, d);
      sm += d;
    }
    mx = fmaxf(mx, __shfl_xor(mx, 16));
    mx = fmaxf(mx, __shfl_xor(mx, 32));
    sm += __shfl_xor(sm, 16);
    sm += __shfl_xor(sm, 32);
    if (lane == 0) Mout[(size_t)bh * 2048 + n] = mx - sm * (1.0f / (float)KN);
    return;
  }

  // ---- meanv_part ----
  {
    const int vb = bid - 17408;          // 0..255
    const int rc = vb >> 3;
    const int cc = vb & 7;
    const int c = cc * 256 + tid;
    const float* p = V + (size_t)rc * 64 * 2048 + c;
    float acc = 0.f;
#pragma unroll 8
    for (int i = 0; i < 64; ++i) acc += p[(size_t)i * 2048];
    vpart[(size_t)rc * 2048 + c] = acc;
  }
}

// ---------------------------------------------------------------------------
// sel2: topk(32) || meanv_final(8). grid 40.
// ---------------------------------------------------------------------------
__global__ __launch_bounds__(256) void sel2_kernel(
    const float* __restrict__ M, int* __restrict__ Mtop,
    const float* __restrict__ part, float* __restrict__ mnV) {
  __shared__ unsigned keys[2048];
  __shared__ int hist[256];
  __shared__ int suf[256];
  __shared__ int scal[2];
  __shared__ int ties[128];
  __shared__ int cnts[2];
  const int tid = threadIdx.x;

  if (blockIdx.x >= 32) {
    const int c = (blockIdx.x - 32) * 256 + tid;
    float acc = 0.f;
#pragma unroll
    for (int r = 0; r < 32; ++r) acc += part[(size_t)r * 2048 + c];
    mnV[c] = acc * (1.0f / (float)KN);
    return;
  }

  const int bh = blockIdx.x;
  const float* Mrow = M + (size_t)bh * 2048;
#pragma unroll
  for (int i = 0; i < 8; ++i) {
    int j = tid + i * 256;
    unsigned u = __float_as_uint(Mrow[j]);
    keys[j] = (u & 0x80000000u) ? ~u : (u | 0x80000000u);
  }
  if (tid < 2) cnts[tid] = 0;

  unsigned prefix = 0, prefmask = 0;
  int rank = UP;
#pragma unroll
  for (int shift = 24; shift >= 0; shift -= 8) {
    hist[tid] = 0;
    __syncthreads();
#pragma unroll
    for (int i = 0; i < 8; ++i) {
      unsigned k = keys[tid + i * 256];
      if ((k & prefmask) == prefix)
        atomicAdd(&hist[(k >> shift) & 0xFFu], 1);
    }
    __syncthreads();
    suf[tid] = hist[tid];
    __syncthreads();
#pragma unroll
    for (int off = 1; off < 256; off <<= 1) {
      int add = (tid + off < 256) ? suf[tid + off] : 0;
      __syncthreads();
      suf[tid] += add;
      __syncthreads();
    }
    {
      int above = suf[tid] - hist[tid];
      if (above < rank && rank <= suf[tid]) {
        scal[0] = tid;
        scal[1] = rank - above;
      }
    }
    __syncthreads();
    prefix |= ((unsigned)scal[0]) << shift;
    prefmask |= 0xFFu << shift;
    rank = scal[1];
    __syncthreads();
  }
  const unsigned T = prefix;

#pragma unroll
  for (int i = 0; i < 8; ++i) {
    int j = tid + i * 256;
    unsigned k = keys[j];
    if (k > T) {
      int p = atomicAdd(&cnts[0], 1);
      Mtop[bh * UP + p] = j;
    } else if (k == T) {
      int p = atomicAdd(&cnts[1], 1);
      if (p < 128) ties[p] = j;
    }
  }
  __syncthreads();
  if (tid == 0) {
    int base = cnts[0];
    int need = UP - base;
    int tc = cnts[1] < 128 ? cnts[1] : 128;
    for (int s = 0; s < need; ++s) {
      int best = 1 << 30, bj = 0;
      for (int j = 0; j < tc; ++j) {
        int v = ties[j];
        if (v < best) { best = v; bj = j; }
      }
      Mtop[bh * UP + base + s] = best;
      ties[bj] = 1 << 30;
    }
  }
}

// ---------------------------------------------------------------------------
// attnmean: attn_part(1024, R15 verified) || meanout(32). grid 1056.
// ---------------------------------------------------------------------------
#define QG 5   // queries per block
#define NC 4   // n-chunks
__global__ __launch_bounds__(256) void attnmean_kernel(
    const float* __restrict__ Q, const float* __restrict__ Kt,
    const float* __restrict__ V, const int* __restrict__ Mtop,
    float* __restrict__ pmax, float* __restrict__ psum,
    float* __restrict__ pvp, const float* __restrict__ mnV,
    const float* __restrict__ Wo, const float* __restrict__ bo,
    float* __restrict__ mo) {
  __shared__ float qs[QG][64];
  __shared__ float p[QG][512];
  __shared__ float redm[QG][4];
  __shared__ float reds[QG][4];
  __shared__ float pvs[4][QG][64];
  const int tid = threadIdx.x;

  if (blockIdx.x >= 1024) {
    // ---- meanout ----
    const int mb = blockIdx.x - 1024;       // 0..31
    const int b = mb >> 3;
    const int oc = mb & 7;
    const int ol = tid & 63;
    const int kp = tid >> 6;
    const int o = oc * 64 + ol;
    const float* m = mnV + b * 512;
    const float* w = Wo + (size_t)o * 512;
    float acc = 0.f;
#pragma unroll 8
    for (int k = kp * 128; k < kp * 128 + 128; ++k)
      acc = fmaf(m[k], w[k], acc);
    __shared__ float red[4][64];
    red[kp][ol] = acc;
    __syncthreads();
    if (tid < 64) {
      float s = red[0][ol] + red[1][ol] + red[2][ol] + red[3][ol];
      mo[b * 512 + o] = s + bo[o];
    }
    return;
  }

  const int bh = blockIdx.x & 31;
  const int t  = blockIdx.x >> 5;
  const int g  = t & 7;
  const int ch = t >> 3;
  const int b = bh >> 3, h = bh & 7;
  const int wv = tid >> 6, lane = tid & 63;
  const int n0 = ch * 512;

  for (int i = tid; i < QG * 64; i += 256) {
    int q = i >> 6, e = i & 63;
    int nq = Mtop[bh * UP + g * QG + q];
    qs[q][e] = Q[(((size_t)nq * 4 + b) * 8 + h) * 64 + e];
  }
  __syncthreads();

  const float* ktb = Kt + (size_t)bh * 64 * 2048;
  float d0[QG] = {}, d1[QG] = {};
  const int nb = n0 + tid * 2;
  for (int e = 0; e < 64; ++e) {
    float2 kv = *(const float2*)(ktb + (size_t)e * 2048 + nb);
#pragma unroll
    for (int q = 0; q < QG; ++q) {
      float qe = qs[q][e];
      d0[q] = fmaf(qe, kv.x, d0[q]);
      d1[q] = fmaf(qe, kv.y, d1[q]);
    }
  }

#pragma unroll
  for (int q = 0; q < QG; ++q) {
    float m_ = fmaxf(d0[q], d1[q]);
#pragma unroll
    for (int off = 1; off < 64; off <<= 1)
      m_ = fmaxf(m_, __shfl_xor(m_, off));
    if (lane == 0) redm[q][wv] = m_;
  }
  __syncthreads();
  float gm[QG];
#pragma unroll
  for (int q = 0; q < QG; ++q)
    gm[q] = fmaxf(fmaxf(redm[q][0], redm[q][1]),
                  fmaxf(redm[q][2], redm[q][3]));

  float ls[QG];
#pragma unroll
  for (int q = 0; q < QG; ++q) {
    float e0 = __expf(d0[q] - gm[q]);
    float e1 = __expf(d1[q] - gm[q]);
    p[q][tid * 2] = e0;
    p[q][tid * 2 + 1] = e1;
    ls[q] = e0 + e1;
  }
#pragma unroll
  for (int q = 0; q < QG; ++q) {
    float s_ = ls[q];
#pragma unroll
    for (int off = 1; off < 64; off <<= 1)
      s_ += __shfl_xor(s_, off);
    if (lane == 0) reds[q][wv] = s_;
  }
  __syncthreads();
  float den[QG];
#pragma unroll
  for (int q = 0; q < QG; ++q)
    den[q] = reds[q][0] + reds[q][1] + reds[q][2] + reds[q][3];

  float acc[QG] = {};
  for (int nn = wv * 128; nn < wv * 128 + 128; ++nn) {
    float v = V[(((size_t)(n0 + nn) * 4 + b) * 8 + h) * 64 + lane];
#pragma unroll
    for (int q = 0; q < QG; ++q) acc[q] = fmaf(p[q][nn], v, acc[q]);
  }
#pragma unroll
  for (int q = 0; q < QG; ++q) pvs[wv][q][lane] = acc[q];
  __syncthreads();

  for (int i = tid; i < QG * 64; i += 256) {
    int q = i >> 6, e = i & 63;
    int slot = bh * UP + g * QG + q;
    float pv = pvs[0][q][e] + pvs[1][q][e] + pvs[2][q][e] + pvs[3][q][e];
    pvp[((size_t)slot * NC + ch) * 64 + e] = pv;
    if (e == 0) {
      pmax[slot * NC + ch] = gm[q];
      psum[slot * NC + ch] = den[q];
    }
  }
}

// ---------------------------------------------------------------------------
// fill2: fillsel(1280) || fillout(4096). grid 5376. Disjoint outputs.
// ---------------------------------------------------------------------------
__global__ __launch_bounds__(256) void fill2_kernel(
    const int* __restrict__ Mtop, const float* __restrict__ mnV,
    float* __restrict__ ctx, const float* __restrict__ mo,
    float* __restrict__ out) {
  const int tid = threadIdx.x;
  if (blockIdx.x < 1280) {
    if (tid < 128) {
      const int i = blockIdx.x;
      const int b = (i / UP) >> 3;
      const int row = b * 2048 + Mtop[i];
      float4 v = *(const float4*)(mnV + b * 512 + tid * 4);
      *(float4*)(ctx + (size_t)row * 512 + tid * 4) = v;
    }
    return;
  }
  size_t i = ((size_t)(blockIdx.x - 1280) * 256 + tid) * 4;
  int d = (int)(i & 511);
  int b = (int)(i >> 20);
  float4 v = *(const float4*)(mo + (b << 9) + d);
  *(float4*)(out + i) = v;
}

// ---------------------------------------------------------------------------
// combine_scatter: flash-combine the NC chunk partials and write the result
// DIRECTLY into ctx (h-slices disjoint per slot -> deterministic).
// ---------------------------------------------------------------------------
__global__ __launch_bounds__(64) void combine_scatter_kernel(
    const float* __restrict__ pmax, const float* __restrict__ psum,
    const float* __restrict__ pvp, const int* __restrict__ Mtop,
    float* __restrict__ ctx) {
  const int slot = blockIdx.x;     // bh*40 + s
  const int e = threadIdx.x;
  const int bh = slot / UP;
  const int b = bh >> 3, h = bh & 7;
  const int n = Mtop[slot];
  float m = -INFINITY;
#pragma unroll
  for (int ch = 0; ch < NC; ++ch) m = fmaxf(m, pmax[slot * NC + ch]);
  float den = 0.f, num = 0.f;
#pragma unroll
  for (int ch = 0; ch < NC; ++ch) {
    float w = __expf(pmax[slot * NC + ch] - m);
    den = fmaf(w, psum[slot * NC + ch], den);
    num = fmaf(w, pvp[((size_t)slot * NC + ch) * 64 + e], num);
  }
  ctx[((size_t)(b * 2048 + n)) * 512 + h * 64 + e] = num / den;
}

// ---------------------------------------------------------------------------
// Sparse output GEMM over the 1280 Mtop rows (R23, verified).
// ---------------------------------------------------------------------------
__global__ __launch_bounds__(256) void gemm_rows(
    const float* __restrict__ ctx, const float* __restrict__ W,
    const float* __restrict__ bias, const int* __restrict__ Mtop,
    float* __restrict__ out) {
  __shared__ float As[32][36];
  __shared__ float Ws[32][68];
  __shared__ int rsel[32];
  const int rt = blockIdx.x >> 3;
  const int ot = blockIdx.x & 7;
  const int o0 = ot * 64;
  const int tid = threadIdx.x;
  const int tx = tid & 15;
  const int ty = tid >> 4;

  if (tid < 32) {
    int g = rt * 32 + tid;
    int b = (g / UP) >> 3;
    rsel[tid] = b * 2048 + Mtop[g];
  }
  __syncthreads();

  float acc[2][4] = {};
  for (int k0 = 0; k0 < 512; k0 += 32) {
    {
      int row = tid >> 3, q = tid & 7;
      float4 av = *(const float4*)(ctx + (size_t)rsel[row] * 512 + k0 + q * 4);
      As[q * 4 + 0][row] = av.x; As[q * 4 + 1][row] = av.y;
      As[q * 4 + 2][row] = av.z; As[q * 4 + 3][row] = av.w;
    }
#pragma unroll
    for (int i = 0; i < 2; ++i) {
      int flat = tid + i * 256;
      int r = flat >> 3, q = flat & 7;
      float4 wv = *(const float4*)(W + (size_t)(o0 + r) * 512 + k0 + q * 4);
      Ws[q * 4 + 0][r] = wv.x; Ws[q * 4 + 1][r] = wv.y;
      Ws[q * 4 + 2][r] = wv.z; Ws[q * 4 + 3][r] = wv.w;
    }
    __syncthreads();
#pragma unroll
    for (int kk = 0; kk < 32; ++kk) {
      float a_[2], w_[4];
#pragma unroll
      for (int i = 0; i < 2; ++i) a_[i] = As[kk][ty * 2 + i];
#pragma unroll
      for (int j = 0; j < 4; ++j) w_[j] = Ws[kk][tx * 4 + j];
#pragma unroll
      for (int i = 0; i < 2; ++i)
#pragma unroll
        for (int j = 0; j < 4; ++j)
          acc[i][j] = fmaf(a_[i], w_[j], acc[i][j]);
    }
    __syncthreads();
  }

#pragma unroll
  for (int i = 0; i < 2; ++i) {
    int m = rsel[ty * 2 + i];
#pragma unroll
    for (int j = 0; j < 4; ++j) {
      int o = o0 + tx * 4 + j;
      out[(size_t)m * 512 + o] = acc[i][j] + bias[o];
    }
  }
}

// ---------------------------------------------------------------------------
// Workspace layout (~70 MiB used; ws >= 113 MiB proven in R4):
//   [0, 256K) Mbuf | [589824,598016) mnV | [598016,603136) Mtop
//   [634880,897024) vpart | [941312,949504) mo
//   [1M,49M) QKV stacked (Q 1-17M = ctx alias, K 17-33M, V 33-49M)
//   [49M,65M) Kt | [65M,66.5M) Wh3 | [66.5M,68M) Wl3
//   [68M..68M+64K) pmax/psum | [..~69.4M) pvp
// ---------------------------------------------------------------------------
extern "C" void kernel_launch(void* const* d_in, const int* in_sizes, int n_in,
                              void* d_out, int out_size, void* d_ws,
                              size_t ws_size, hipStream_t stream) {
  const float* query = (const float*)d_in[0];
  const float* key   = (const float*)d_in[1];
  const float* value = (const float*)d_in[2];
  const int*   idxs  = (const int*)d_in[3];
  const float* Wq = (const float*)d_in[4];
  const float* bq = (const float*)d_in[5];
  const float* Wk = (const float*)d_in[6];
  const float* bk = (const float*)d_in[7];
  const float* Wv = (const float*)d_in[8];
  const float* bv = (const float*)d_in[9];
  const float* Wo = (const float*)d_in[10];
  const float* bo = (const float*)d_in[11];
  float* out = (float*)d_out;    // reference output dtype is float32

  char* ws = (char*)d_ws;
  float*  Mbuf  = (float*)(ws + 0);
  float*  mnV   = (float*)(ws + 589824);
  int*    Mtop  = (int*)  (ws + 598016);
  float*  vpart = (float*)(ws + 634880);
  float*  mo    = (float*)(ws + 941312);
  float*  QKV   = (float*)(ws + MiB(1));   // Q | K | V stacked
  float*  Q     = QKV;
  float*  K     = (float*)(ws + MiB(17));
  float*  V     = (float*)(ws + MiB(33));
  float*  Kt    = (float*)(ws + MiB(49));
  ushort* Wh3   = (ushort*)(ws + MiB(65));
  ushort* Wl3   = (ushort*)(ws + MiB(65) + 1572864);
  float*  pmax  = (float*)(ws + MiB(68));
  float*  psum  = (float*)(ws + MiB(68) + 32768);
  float*  pvp   = (float*)(ws + MiB(68) + 65536);
  float*  ctx   = Q;   // Q dead after attn; ctx written afterwards

  wsplit3_kernel<<<1536, 256, 0, stream>>>(Wq, Wk, Wv, Wh3, Wl3);
  gemm3_mfma<<<768, 256, 0, stream>>>(query, key, value, Wh3, Wl3,
                                      bq, bk, bv, QKV);

  prep3_kernel<<<17664, 256, 0, stream>>>(K, Kt, Q, idxs, Mbuf, V, vpart);
  sel2_kernel<<<40, 256, 0, stream>>>(Mbuf, Mtop, vpart, mnV);

  attnmean_kernel<<<1056, 256, 0, stream>>>(Q, Kt, V, Mtop, pmax, psum, pvp,
                                            mnV, Wo, bo, mo);
  fill2_kernel<<<5376, 256, 0, stream>>>(Mtop, mnV, ctx, mo, out);
  combine_scatter_kernel<<<NBH * UP, 64, 0, stream>>>(pmax, psum, pvp,
                                                      Mtop, ctx);
  gemm_rows<<<320, 256, 0, stream>>>(ctx, Wo, bo, Mtop, out);
}